// Round 4
// baseline (548.710 us; speedup 1.0000x reference)
//
#include <hip/hip_runtime.h>

// WarpingLayer_3stacks: trilinear scatter-splat (grid_push) of
// intensities = [x*mask, mask] into 128^3, coords = flow + meshgrid.
// Input 384x128x128. Output [1,2,128,128,128] f32.
//
// R1: global f32 atomicAdd ~22G/s is the wall. R2: LDS privatization works
// but 512/256-block grids = 2/1 blocks/CU -> latency-bound at 8/4 waves/CU
// (VALUBusy 15%, Occ 20%). R3: max out parallelism.
//  - gather (z<128): 2x4x128 owned output tiles -> 2048 blocks, 32 waves/CU,
//    early-skip of non-contributing halo points.
//  - plane (z>=128): full 128x128 plane per channel in 64KB LDS, 512 blocks
//    (256 z-slabs x 2 ch) x 1024 thr = 32 waves/CU; plain-store partial
//    planes to ws, bandwidth-bound combine. Zero flush atomics.

#define OS    128
#define OS3   (OS * OS * OS)
#define SRC_D 384
#define SRC_H 128
#define SRC_W 128
#define NSRC  (SRC_D * SRC_H * SRC_W)
#define ZSPLIT 128
#define PLANE_CELLS (OS * OS)     // 16384

// gather tiling
#define TZ 2
#define TY 4
#define HALO 3

// Path-B (low-ws fallback) plane tiling
#define ZC 16
#define TH 16
#define TW 64
#define PPAD 4
#define LDSH (TH + 2 * PPAD)
#define LDSW (TW + 2 * PPAD)

// Generic 8-corner scatter with replicate clamping (rare fallback).
__device__ __forceinline__ void scatter_global(float* __restrict__ dst,
                                               float v0, float m,
                                               float gz, float gy, float gx)
{
    float fz0 = floorf(gz), fy0 = floorf(gy), fx0 = floorf(gx);
    float fz = gz - fz0, fy = gy - fy0, fx = gx - fx0;
    int iz0 = (int)fz0, iy0 = (int)fy0, ix0 = (int)fx0;

    #pragma unroll
    for (int dz = 0; dz < 2; ++dz) {
        int cz = min(max(iz0 + dz, 0), OS - 1);
        float wz = dz ? fz : 1.0f - fz;
        #pragma unroll
        for (int dy = 0; dy < 2; ++dy) {
            int cy = min(max(iy0 + dy, 0), OS - 1);
            float wzy = wz * (dy ? fy : 1.0f - fy);
            #pragma unroll
            for (int dx = 0; dx < 2; ++dx) {
                int cx = min(max(ix0 + dx, 0), OS - 1);
                float wgt = wzy * (dx ? fx : 1.0f - fx);
                int o = (cz << 14) + (cy << 7) + cx;
                atomicAdd(dst + o,       v0 * wgt);
                atomicAdd(dst + OS3 + o, m  * wgt);
            }
        }
    }
}

// -------- gather kernel: source z in [0,128), output-tile ownership --------
// grid (64, 32) = 2048 blocks. Block owns out[z0:z0+2][y0:y0+4][0:128].
__global__ __launch_bounds__(256, 8) void warp_gather(
    const float* __restrict__ x,
    const float* __restrict__ flow,
    const float* __restrict__ mask,
    float* __restrict__ out,
    float* __restrict__ ovf,        // fallback target (ws partial, or out)
    int atomic_flush)
{
    __shared__ float acc[2][TZ][TY][OS];   // 8 KB

    int tid = threadIdx.x;
    for (int i = tid; i < 2 * TZ * TY * OS; i += 256)
        ((float*)acc)[i] = 0.0f;
    __syncthreads();

    int z0 = blockIdx.x * TZ;
    int y0 = blockIdx.y * TY;
    int zlo = max(z0 - HALO, 0), zhi = min(z0 + TZ + HALO, ZSPLIT);
    int ylo = max(y0 - HALO, 0), yhi = min(y0 + TY + HALO, OS);

    int w  = tid & 127;
    int yh = tid >> 7;     // 0/1

    for (int zz = zlo; zz < zhi; ++zz) {
        for (int yb = ylo; yb < yhi; yb += 2) {
            int hh = yb + yh;
            if (hh >= yhi) continue;
            int idx = (zz << 14) + (hh << 7) + w;

            float gz = flow[idx]        + (float)zz;
            float gy = flow[NSRC + idx] + (float)hh;
            float fz0 = floorf(gz), fy0 = floorf(gy);
            float fz = gz - fz0, fy = gy - fy0;
            int iz0 = (int)fz0, iy0 = (int)fy0;

            int cz0 = min(max(iz0,     0), OS - 1);
            int cz1 = min(max(iz0 + 1, 0), OS - 1);
            int cy0 = min(max(iy0,     0), OS - 1);
            int cy1 = min(max(iy0 + 1, 0), OS - 1);

            bool home = (zz >= z0) && (zz < z0 + TZ) &&
                        (hh >= y0) && (hh < y0 + TY);
            bool zin = (cz1 >= z0) && (cz0 < z0 + TZ);
            bool yin = (cy1 >= y0) && (cy0 < y0 + TY);
            if (!home && !(zin && yin)) continue;   // prunes ~74% of halo pts

            float gx = flow[2 * NSRC + idx] + (float)w;
            float fx0 = floorf(gx);
            float fx = gx - fx0;
            int ix0 = (int)fx0;
            int cx0 = min(max(ix0,     0), OS - 1);
            int cx1 = min(max(ix0 + 1, 0), OS - 1);

            float m = mask[idx];
            float v = x[idx] * m;

            #pragma unroll
            for (int dz = 0; dz < 2; ++dz) {
                int cz = dz ? cz1 : cz0;
                float wz = dz ? fz : 1.0f - fz;
                bool nz = abs(cz - zz) <= HALO;
                int uz = cz - z0;
                #pragma unroll
                for (int dy = 0; dy < 2; ++dy) {
                    int cy = dy ? cy1 : cy0;
                    float wzy = wz * (dy ? fy : 1.0f - fy);
                    bool ny = abs(cy - hh) <= HALO;
                    int uy = cy - y0;
                    #pragma unroll
                    for (int dx = 0; dx < 2; ++dx) {
                        int cx = dx ? cx1 : cx0;
                        float wgt = wzy * (dx ? fx : 1.0f - fx);
                        if (nz && ny) {
                            if ((unsigned)uz < TZ && (unsigned)uy < TY) {
                                atomicAdd(&acc[0][uz][uy][cx], v * wgt);
                                atomicAdd(&acc[1][uz][uy][cx], m * wgt);
                            }
                        } else if (home) {
                            int o = (cz << 14) + (cy << 7) + cx;
                            atomicAdd(ovf + o,       v * wgt);
                            atomicAdd(ovf + OS3 + o, m * wgt);
                        }
                    }
                }
            }
        }
    }

    __syncthreads();

    // flush owned tile (contiguous, coalesced)
    for (int i = tid; i < 2 * TZ * TY * OS; i += 256) {
        int ch   = i >> 10;            // / (TZ*TY*OS = 1024)
        int rem  = i & 1023;
        int dz   = rem >> 9;           // / (TY*OS = 512)
        int rem2 = rem & 511;
        int o = ch * OS3 + ((z0 + dz) << 14) + (y0 << 7) + rem2;
        float val = ((float*)acc)[i];
        if (atomic_flush) atomicAdd(out + o, val);
        else              out[o] = val;
    }
}

// ---- plane kernel (Path A): z in [128,384), full-plane LDS per channel ----
// grid (G, 2): blockIdx.x = slab group, blockIdx.y = channel. 1024 threads.
__global__ __launch_bounds__(1024, 8) void warp_plane_partial(
    const float* __restrict__ x,
    const float* __restrict__ flow,
    const float* __restrict__ mask,
    float* __restrict__ partials,   // [G][2][PLANE_CELLS]
    float* __restrict__ ovf,
    int spb)                        // slabs per block = 256/G
{
    __shared__ float pl[PLANE_CELLS];   // 64 KB

    int tid = threadIdx.x;
    int ch  = blockIdx.y;
    for (int i = tid; i < PLANE_CELLS; i += 1024) pl[i] = 0.0f;
    __syncthreads();

    int w  = tid & 127;
    int r0 = tid >> 7;     // 0..7

    for (int s = 0; s < spb; ++s) {
        int z = ZSPLIT + blockIdx.x * spb + s;
        for (int r = r0; r < OS; r += 8) {     // 16 iters
            int idx = (z << 14) + (r << 7) + w;

            float gz = flow[idx]            + (float)z;
            float gy = flow[NSRC + idx]     + (float)r;
            float gx = flow[2 * NSRC + idx] + (float)w;
            float m  = mask[idx];

            if (gz >= (float)(OS - 1)) {       // both z-corners clamp to 127
                float v;
                if (ch == 0) v = x[idx] * m; else v = m;

                float fy0 = floorf(gy), fx0 = floorf(gx);
                float fy = gy - fy0, fx = gx - fx0;
                int iy0 = (int)fy0, ix0 = (int)fx0;
                int cy0 = min(max(iy0,     0), OS - 1);
                int cy1 = min(max(iy0 + 1, 0), OS - 1);
                int cx0 = min(max(ix0,     0), OS - 1);
                int cx1 = min(max(ix0 + 1, 0), OS - 1);

                atomicAdd(&pl[(cy0 << 7) + cx0], v * (1.0f - fy) * (1.0f - fx));
                atomicAdd(&pl[(cy0 << 7) + cx1], v * (1.0f - fy) * fx);
                atomicAdd(&pl[(cy1 << 7) + cx0], v * fy * (1.0f - fx));
                atomicAdd(&pl[(cy1 << 7) + cx1], v * fy * fx);
            } else if (ch == 0) {
                // rare: z in [128,~130) with flow_z < z-127 -> generic scatter
                float v0 = x[idx] * m;
                scatter_global(ovf, v0, m, gz, gy, gx);
            }
        }
    }

    __syncthreads();

    float* dst = partials + ((size_t)(blockIdx.x * 2 + ch)) * PLANE_CELLS;
    for (int i = tid; i < PLANE_CELLS; i += 1024) dst[i] = pl[i];
}

// out += ovf (whole volume), float4
__global__ __launch_bounds__(256) void combine_ws(float* __restrict__ out,
                                                  const float* __restrict__ ovf)
{
    int i = blockIdx.x * blockDim.x + threadIdx.x;
    float4 a = ((float4*)out)[i];
    float4 b = ((const float4*)ovf)[i];
    a.x += b.x; a.y += b.y; a.z += b.z; a.w += b.w;
    ((float4*)out)[i] = a;
}

// out[z=127 plane] += sum_g partials[g]
__global__ __launch_bounds__(256) void combine_plane(float* __restrict__ out,
                                                     const float* __restrict__ partials,
                                                     int G)
{
    int c = blockIdx.x * blockDim.x + threadIdx.x;   // 0 .. 2*16384-1
    int ch   = c >> 14;
    int cell = c & (PLANE_CELLS - 1);
    float s = 0.0f;
    for (int g = 0; g < G; ++g)
        s += partials[((size_t)(g * 2 + ch)) * PLANE_CELLS + cell];
    out[ch * OS3 + ((OS - 1) << 14) + cell] += s;
}

// ---------------- Path B fallback plane kernel (R2-style) ----------------
__global__ __launch_bounds__(256) void warp_push_plane(
    const float* __restrict__ x,
    const float* __restrict__ flow,
    const float* __restrict__ mask,
    float* __restrict__ out)
{
    __shared__ float tile[2][LDSH][LDSW];

    int tid = threadIdx.x;
    for (int i = tid; i < 2 * LDSH * LDSW; i += 256)
        ((float*)tile)[i] = 0.0f;
    __syncthreads();

    int w0 = blockIdx.x * TW;
    int h0 = blockIdx.y * TH;
    int z0 = ZSPLIT + blockIdx.z * ZC;

    int dw  = tid & 63;
    int sub = tid >> 6;
    const int hlo = h0 - PPAD, wlo = w0 - PPAD;

    for (int it = 0; it < (ZC * TH * TW) / 256; ++it) {
        int pair = it * 4 + sub;
        int dh = pair & (TH - 1);
        int dz = pair >> 4;
        int z = z0 + dz, h = h0 + dh, w = w0 + dw;
        int idx = (z * SRC_H + h) * SRC_W + w;

        float gz = flow[idx]            + (float)z;
        float gy = flow[NSRC + idx]     + (float)h;
        float gx = flow[2 * NSRC + idx] + (float)w;
        float m  = mask[idx];
        float v0 = x[idx] * m;

        float fy0 = floorf(gy), fx0 = floorf(gx);
        float fy = gy - fy0, fx = gx - fx0;
        int iy0 = (int)fy0, ix0 = (int)fx0;
        int iyc0 = min(max(iy0,     0), OS - 1);
        int iyc1 = min(max(iy0 + 1, 0), OS - 1);
        int ixc0 = min(max(ix0,     0), OS - 1);
        int ixc1 = min(max(ix0 + 1, 0), OS - 1);

        bool clampedZ = (gz >= (float)(OS - 1));
        bool inTile = (iyc0 >= hlo) && (iyc1 < hlo + LDSH) &&
                      (ixc0 >= wlo) && (ixc1 < wlo + LDSW);

        if (clampedZ && inTile) {
            int r0 = iyc0 - hlo, r1 = iyc1 - hlo;
            int c0 = ixc0 - wlo, c1 = ixc1 - wlo;
            atomicAdd(&tile[0][r0][c0], v0 * (1.0f - fy) * (1.0f - fx));
            atomicAdd(&tile[1][r0][c0], m  * (1.0f - fy) * (1.0f - fx));
            atomicAdd(&tile[0][r0][c1], v0 * (1.0f - fy) * fx);
            atomicAdd(&tile[1][r0][c1], m  * (1.0f - fy) * fx);
            atomicAdd(&tile[0][r1][c0], v0 * fy * (1.0f - fx));
            atomicAdd(&tile[1][r1][c0], m  * fy * (1.0f - fx));
            atomicAdd(&tile[0][r1][c1], v0 * fy * fx);
            atomicAdd(&tile[1][r1][c1], m  * fy * fx);
        } else {
            scatter_global(out, v0, m, gz, gy, gx);
        }
    }

    __syncthreads();

    const int planeBase = (OS - 1) << 14;
    for (int i = tid; i < 2 * LDSH * LDSW; i += 256) {
        int ch  = i / (LDSH * LDSW);
        int rem = i - ch * (LDSH * LDSW);
        int r = rem / LDSW;
        int c = rem - r * LDSW;
        int y = hlo + r, xo = wlo + c;
        if ((unsigned)y < OS && (unsigned)xo < OS) {
            float v = ((float*)tile)[i];
            if (v != 0.0f)
                atomicAdd(out + ch * OS3 + planeBase + (y << 7) + xo, v);
        }
    }
}

extern "C" void kernel_launch(void* const* d_in, const int* in_sizes, int n_in,
                              void* d_out, int out_size, void* d_ws, size_t ws_size,
                              hipStream_t stream) {
    const float* x    = (const float*)d_in[0];
    const float* flow = (const float*)d_in[1];
    const float* mask = (const float*)d_in[2];
    float* out = (float*)d_out;

    const size_t outBytes   = (size_t)2 * OS3 * sizeof(float);       // 16.78 MB
    const size_t planeBytes = (size_t)2 * PLANE_CELLS * sizeof(float); // 128 KB

    int G = 0;
    if      (ws_size >= outBytes + 256 * planeBytes / 2 * 2) G = 256; // 50.3 MB
    else if (ws_size >= outBytes + 128 * planeBytes)         G = 128;
    else if (ws_size >= outBytes +  64 * planeBytes)         G = 64;
    else if (ws_size >= outBytes +  32 * planeBytes)         G = 32;

    dim3 ggrid(OS / TZ, OS / TY);   // (64, 32) = 2048 blocks

    if (G) {
        float* ovf      = (float*)d_ws;
        float* partials = (float*)((char*)d_ws + outBytes);
        hipMemsetAsync(d_ws, 0, outBytes, stream);

        warp_gather<<<ggrid, 256, 0, stream>>>(x, flow, mask, out, ovf, 0);

        dim3 pgrid(G, 2);
        warp_plane_partial<<<pgrid, 1024, 0, stream>>>(x, flow, mask,
                                                       partials, ovf, 256 / G);

        combine_ws<<<(2 * OS3 / 4) / 256, 256, 0, stream>>>(out, ovf);
        combine_plane<<<(2 * PLANE_CELLS) / 256, 256, 0, stream>>>(out, partials, G);
    } else {
        hipMemsetAsync(d_out, 0, outBytes, stream);
        warp_gather<<<ggrid, 256, 0, stream>>>(x, flow, mask, out, out, 1);
        dim3 pgrid(SRC_W / TW, SRC_H / TH, (SRC_D - ZSPLIT) / ZC);
        warp_push_plane<<<pgrid, 256, 0, stream>>>(x, flow, mask, out);
    }
}

// Round 5
// 496.937 us; speedup vs baseline: 1.1042x; 1.1042x over previous
//
#include <hip/hip_runtime.h>

// WarpingLayer_3stacks: trilinear scatter-splat (grid_push) of
// intensities = [x*mask, mask] into 128^3, coords = flow + meshgrid.
// Input 384x128x128. Output [1,2,128,128,128] f32.
//
// R1: global f32 atomicAdd ~22G/s is the wall -> privatize in LDS.
// R2: privatization works but needs >=32 waves/CU (latency hiding).
// R3: gather 198us at VALUBusy 26% -> still latency-bound; scan amp 10x,
//     VGPR=20 (no ILP). R4: 4x4 tiles @512thr (amp 6.25, 32 waves/CU),
//     fixed-trip unrolled scan with unconditional clamped loads (ILP),
//     plane kernel unconditional loads + unroll, fused combine.

#define OS    128
#define OS3   (OS * OS * OS)
#define SRC_D 384
#define SRC_H 128
#define SRC_W 128
#define NSRC  (SRC_D * SRC_H * SRC_W)
#define ZSPLIT 128
#define PLANE_CELLS (OS * OS)     // 16384

// gather tiling
#define TZ 4
#define TY 4
#define HALO 3
#define NZSCAN (TZ + 2 * HALO)    // 10

// Path-B (low-ws fallback) plane tiling
#define ZC 16
#define TH 16
#define TW 64
#define PPAD 4
#define LDSH (TH + 2 * PPAD)
#define LDSW (TW + 2 * PPAD)

// Generic 8-corner scatter with replicate clamping (rare fallback).
__device__ __forceinline__ void scatter_global(float* __restrict__ dst,
                                               float v0, float m,
                                               float gz, float gy, float gx)
{
    float fz0 = floorf(gz), fy0 = floorf(gy), fx0 = floorf(gx);
    float fz = gz - fz0, fy = gy - fy0, fx = gx - fx0;
    int iz0 = (int)fz0, iy0 = (int)fy0, ix0 = (int)fx0;

    #pragma unroll
    for (int dz = 0; dz < 2; ++dz) {
        int cz = min(max(iz0 + dz, 0), OS - 1);
        float wz = dz ? fz : 1.0f - fz;
        #pragma unroll
        for (int dy = 0; dy < 2; ++dy) {
            int cy = min(max(iy0 + dy, 0), OS - 1);
            float wzy = wz * (dy ? fy : 1.0f - fy);
            #pragma unroll
            for (int dx = 0; dx < 2; ++dx) {
                int cx = min(max(ix0 + dx, 0), OS - 1);
                float wgt = wzy * (dx ? fx : 1.0f - fx);
                int o = (cz << 14) + (cy << 7) + cx;
                atomicAdd(dst + o,       v0 * wgt);
                atomicAdd(dst + OS3 + o, m  * wgt);
            }
        }
    }
}

// -------- gather kernel: source z in [0,128), output-tile ownership --------
// grid (32, 32) = 1024 blocks x 512 thr. Block owns out[z0:z0+4][y0:y0+4][:].
// Scan region: z,y within +-HALO of the tile. Every corner of every point is
// either accumulated by the block owning it (point within HALO) or routed to
// ovf by the point's home block.
__global__ __launch_bounds__(512, 8) void warp_gather(
    const float* __restrict__ x,
    const float* __restrict__ flow,
    const float* __restrict__ mask,
    float* __restrict__ out,
    float* __restrict__ ovf,
    int atomic_flush)
{
    __shared__ float acc[2][TZ][TY][OS];   // 16 KB

    int tid = threadIdx.x;
    for (int i = tid; i < 2 * TZ * TY * OS; i += 512)
        ((float*)acc)[i] = 0.0f;
    __syncthreads();

    const int z0 = blockIdx.x * TZ;
    const int y0 = blockIdx.y * TY;
    const int w  = tid & 127;
    const int yh = tid >> 7;     // 0..3

    const float* __restrict__ fz_p = flow;
    const float* __restrict__ fy_p = flow + NSRC;
    const float* __restrict__ fx_p = flow + 2 * NSRC;

    for (int dzz = 0; dzz < NZSCAN; ++dzz) {
        int zzr = z0 - HALO + dzz;
        int zz  = min(max(zzr, 0), ZSPLIT - 1);
        bool vz = (zzr >= 0) && (zzr < ZSPLIT);

        #pragma unroll
        for (int g = 0; g < 3; ++g) {          // rows y0-3 .. y0+8 (12 slots)
            int hhr = y0 - HALO + g * 4 + yh;
            int hh  = min(max(hhr, 0), OS - 1);
            bool vrow = vz && (hhr >= 0) && (hhr < OS);

            int idx = (zz << 14) + (hh << 7) + w;
            float fzl = fz_p[idx];             // unconditional clamped loads
            float fyl = fy_p[idx];

            float gz = fzl + (float)zz;
            float gy = fyl + (float)hh;
            float fz0 = floorf(gz), fy0 = floorf(gy);
            float fz = gz - fz0, fy = gy - fy0;
            int iz0 = (int)fz0, iy0 = (int)fy0;

            int cz0 = min(max(iz0,     0), OS - 1);
            int cz1 = min(max(iz0 + 1, 0), OS - 1);
            int cy0 = min(max(iy0,     0), OS - 1);
            int cy1 = min(max(iy0 + 1, 0), OS - 1);

            bool home = (zzr >= z0) && (zzr < z0 + TZ) &&
                        (hhr >= y0) && (hhr < y0 + TY);
            bool zin = (cz1 >= z0) && (cz0 < z0 + TZ);
            bool yin = (cy1 >= y0) && (cy0 < y0 + TY);
            if (!vrow || (!home && !(zin && yin))) continue;

            float gx = fx_p[idx] + (float)w;
            float fx0 = floorf(gx);
            float fx = gx - fx0;
            int ix0 = (int)fx0;
            int cx0 = min(max(ix0,     0), OS - 1);
            int cx1 = min(max(ix0 + 1, 0), OS - 1);

            float m = mask[idx];
            float v = x[idx] * m;

            #pragma unroll
            for (int dz = 0; dz < 2; ++dz) {
                int cz = dz ? cz1 : cz0;
                float wz = dz ? fz : 1.0f - fz;
                bool nz = abs(cz - zz) <= HALO;
                int uz = cz - z0;
                #pragma unroll
                for (int dy = 0; dy < 2; ++dy) {
                    int cy = dy ? cy1 : cy0;
                    float wzy = wz * (dy ? fy : 1.0f - fy);
                    bool ny = abs(cy - hh) <= HALO;
                    int uy = cy - y0;
                    #pragma unroll
                    for (int dx = 0; dx < 2; ++dx) {
                        int cx = dx ? cx1 : cx0;
                        float wgt = wzy * (dx ? fx : 1.0f - fx);
                        if (nz && ny) {
                            if ((unsigned)uz < TZ && (unsigned)uy < TY) {
                                atomicAdd(&acc[0][uz][uy][cx], v * wgt);
                                atomicAdd(&acc[1][uz][uy][cx], m * wgt);
                            }
                        } else if (home) {
                            int o = (cz << 14) + (cy << 7) + cx;
                            atomicAdd(ovf + o,       v * wgt);
                            atomicAdd(ovf + OS3 + o, m * wgt);
                        }
                    }
                }
            }
        }
    }

    __syncthreads();

    // flush owned tile (contiguous, coalesced). per-ch floats: TZ*TY*OS = 2048
    for (int i = tid; i < 2 * TZ * TY * OS; i += 512) {
        int ch   = i >> 11;
        int rem  = i & 2047;
        int dz   = rem >> 9;           // / (TY*OS = 512)
        int rem2 = rem & 511;
        int o = ch * OS3 + ((z0 + dz) << 14) + (y0 << 7) + rem2;
        float val = ((float*)acc)[i];
        if (atomic_flush) atomicAdd(out + o, val);
        else              out[o] = val;
    }
}

// ---- plane kernel (Path A): z in [128,384), full-plane LDS per channel ----
// grid (G, 2): blockIdx.x = slab group, blockIdx.y = channel. 1024 threads.
__global__ __launch_bounds__(1024, 8) void warp_plane_partial(
    const float* __restrict__ x,
    const float* __restrict__ flow,
    const float* __restrict__ mask,
    float* __restrict__ partials,   // [G][2][PLANE_CELLS]
    float* __restrict__ ovf,
    int spb)                        // slabs per block = 256/G
{
    __shared__ float pl[PLANE_CELLS];   // 64 KB

    int tid = threadIdx.x;
    int ch  = blockIdx.y;
    for (int i = tid; i < PLANE_CELLS; i += 1024) pl[i] = 0.0f;
    __syncthreads();

    int w  = tid & 127;
    int r0 = tid >> 7;     // 0..7

    // uniform unconditional value load: ch0 -> x, ch1 -> mask (re-read, L1 hit)
    const float* __restrict__ vsrc = (ch == 0) ? x : mask;
    const float* __restrict__ fz_p = flow;
    const float* __restrict__ fy_p = flow + NSRC;
    const float* __restrict__ fx_p = flow + 2 * NSRC;

    for (int s = 0; s < spb; ++s) {
        int z = ZSPLIT + blockIdx.x * spb + s;
        #pragma unroll 2
        for (int r = r0; r < OS; r += 8) {     // 16 iters
            int idx = (z << 14) + (r << 7) + w;

            float fzl = fz_p[idx];
            float fyl = fy_p[idx];
            float fxl = fx_p[idx];
            float m   = mask[idx];
            float vv  = vsrc[idx];

            float gz = fzl + (float)z;
            float gy = fyl + (float)r;
            float gx = fxl + (float)w;
            float v  = (ch == 0) ? vv * m : m;

            float fy0 = floorf(gy), fx0 = floorf(gx);
            float fy = gy - fy0, fx = gx - fx0;
            int iy0 = (int)fy0, ix0 = (int)fx0;
            int cy0 = min(max(iy0,     0), OS - 1);
            int cy1 = min(max(iy0 + 1, 0), OS - 1);
            int cx0 = min(max(ix0,     0), OS - 1);
            int cx1 = min(max(ix0 + 1, 0), OS - 1);

            if (gz >= (float)(OS - 1)) {       // both z-corners clamp to 127
                atomicAdd(&pl[(cy0 << 7) + cx0], v * (1.0f - fy) * (1.0f - fx));
                atomicAdd(&pl[(cy0 << 7) + cx1], v * (1.0f - fy) * fx);
                atomicAdd(&pl[(cy1 << 7) + cx0], v * fy * (1.0f - fx));
                atomicAdd(&pl[(cy1 << 7) + cx1], v * fy * fx);
            } else if (ch == 0) {
                // rare: z in [128,~131) with large negative flow_z
                scatter_global(ovf, vv * m, m, gz, gy, gx);
            }
        }
    }

    __syncthreads();

    float* dst = partials + ((size_t)(blockIdx.x * 2 + ch)) * PLANE_CELLS;
    for (int i = tid; i < PLANE_CELLS; i += 1024) dst[i] = pl[i];
}

// Fused combine: out = out + ovf (+ sum_g partials on the z=127 plane cells)
__global__ __launch_bounds__(256) void combine_all(
    float* __restrict__ out,
    const float* __restrict__ ovf,
    const float* __restrict__ partials,
    int G)
{
    int i = blockIdx.x * blockDim.x + threadIdx.x;   // float4 idx, 2*OS3/4 total
    float4 a = ((const float4*)out)[i];
    float4 b = ((const float4*)ovf)[i];
    a.x += b.x; a.y += b.y; a.z += b.z; a.w += b.w;

    const int pbase = ((OS - 1) << 14) >> 2;     // plane start, float4 units
    const int os3_4 = OS3 >> 2;
    const int pc4   = PLANE_CELLS >> 2;          // 4096

    int ch = -1, c4 = 0;
    if (i >= pbase && i < pbase + pc4)         { ch = 0; c4 = i - pbase; }
    else if (i >= os3_4 + pbase)               { ch = 1; c4 = i - (os3_4 + pbase); }

    if (ch >= 0) {
        const float4* __restrict__ p4 = (const float4*)partials;
        float4 s = make_float4(0.f, 0.f, 0.f, 0.f);
        #pragma unroll 8
        for (int g = 0; g < G; ++g) {
            float4 t = p4[(size_t)(g * 2 + ch) * pc4 + c4];
            s.x += t.x; s.y += t.y; s.z += t.z; s.w += t.w;
        }
        a.x += s.x; a.y += s.y; a.z += s.z; a.w += s.w;
    }
    ((float4*)out)[i] = a;
}

// ---------------- Path B fallback plane kernel (R2-style) ----------------
__global__ __launch_bounds__(256) void warp_push_plane(
    const float* __restrict__ x,
    const float* __restrict__ flow,
    const float* __restrict__ mask,
    float* __restrict__ out)
{
    __shared__ float tile[2][LDSH][LDSW];

    int tid = threadIdx.x;
    for (int i = tid; i < 2 * LDSH * LDSW; i += 256)
        ((float*)tile)[i] = 0.0f;
    __syncthreads();

    int w0 = blockIdx.x * TW;
    int h0 = blockIdx.y * TH;
    int z0 = ZSPLIT + blockIdx.z * ZC;

    int dw  = tid & 63;
    int sub = tid >> 6;
    const int hlo = h0 - PPAD, wlo = w0 - PPAD;

    for (int it = 0; it < (ZC * TH * TW) / 256; ++it) {
        int pair = it * 4 + sub;
        int dh = pair & (TH - 1);
        int dz = pair >> 4;
        int z = z0 + dz, h = h0 + dh, w = w0 + dw;
        int idx = (z * SRC_H + h) * SRC_W + w;

        float gz = flow[idx]            + (float)z;
        float gy = flow[NSRC + idx]     + (float)h;
        float gx = flow[2 * NSRC + idx] + (float)w;
        float m  = mask[idx];
        float v0 = x[idx] * m;

        float fy0 = floorf(gy), fx0 = floorf(gx);
        float fy = gy - fy0, fx = gx - fx0;
        int iy0 = (int)fy0, ix0 = (int)fx0;
        int iyc0 = min(max(iy0,     0), OS - 1);
        int iyc1 = min(max(iy0 + 1, 0), OS - 1);
        int ixc0 = min(max(ix0,     0), OS - 1);
        int ixc1 = min(max(ix0 + 1, 0), OS - 1);

        bool clampedZ = (gz >= (float)(OS - 1));
        bool inTile = (iyc0 >= hlo) && (iyc1 < hlo + LDSH) &&
                      (ixc0 >= wlo) && (ixc1 < wlo + LDSW);

        if (clampedZ && inTile) {
            int r0 = iyc0 - hlo, r1 = iyc1 - hlo;
            int c0 = ixc0 - wlo, c1 = ixc1 - wlo;
            atomicAdd(&tile[0][r0][c0], v0 * (1.0f - fy) * (1.0f - fx));
            atomicAdd(&tile[1][r0][c0], m  * (1.0f - fy) * (1.0f - fx));
            atomicAdd(&tile[0][r0][c1], v0 * (1.0f - fy) * fx);
            atomicAdd(&tile[1][r0][c1], m  * (1.0f - fy) * fx);
            atomicAdd(&tile[0][r1][c0], v0 * fy * (1.0f - fx));
            atomicAdd(&tile[1][r1][c0], m  * fy * (1.0f - fx));
            atomicAdd(&tile[0][r1][c1], v0 * fy * fx);
            atomicAdd(&tile[1][r1][c1], m  * fy * fx);
        } else {
            scatter_global(out, v0, m, gz, gy, gx);
        }
    }

    __syncthreads();

    const int planeBase = (OS - 1) << 14;
    for (int i = tid; i < 2 * LDSH * LDSW; i += 256) {
        int ch  = i / (LDSH * LDSW);
        int rem = i - ch * (LDSH * LDSW);
        int r = rem / LDSW;
        int c = rem - r * LDSW;
        int y = hlo + r, xo = wlo + c;
        if ((unsigned)y < OS && (unsigned)xo < OS) {
            float v = ((float*)tile)[i];
            if (v != 0.0f)
                atomicAdd(out + ch * OS3 + planeBase + (y << 7) + xo, v);
        }
    }
}

extern "C" void kernel_launch(void* const* d_in, const int* in_sizes, int n_in,
                              void* d_out, int out_size, void* d_ws, size_t ws_size,
                              hipStream_t stream) {
    const float* x    = (const float*)d_in[0];
    const float* flow = (const float*)d_in[1];
    const float* mask = (const float*)d_in[2];
    float* out = (float*)d_out;

    const size_t outBytes   = (size_t)2 * OS3 * sizeof(float);         // 16.78 MB
    const size_t planeBytes = (size_t)2 * PLANE_CELLS * sizeof(float); // 128 KB

    int G = 0;
    if      (ws_size >= outBytes + 256 * planeBytes) G = 256;   // 50.3 MB
    else if (ws_size >= outBytes + 128 * planeBytes) G = 128;
    else if (ws_size >= outBytes +  64 * planeBytes) G = 64;
    else if (ws_size >= outBytes +  32 * planeBytes) G = 32;

    if (G) {
        float* ovf      = (float*)d_ws;
        float* partials = (float*)((char*)d_ws + outBytes);
        hipMemsetAsync(d_ws, 0, outBytes, stream);

        dim3 ggrid(OS / TZ, OS / TY);   // (32, 32) = 1024 blocks
        warp_gather<<<ggrid, 512, 0, stream>>>(x, flow, mask, out, ovf, 0);

        dim3 pgrid(G, 2);
        warp_plane_partial<<<pgrid, 1024, 0, stream>>>(x, flow, mask,
                                                       partials, ovf, 256 / G);

        combine_all<<<(2 * OS3 / 4) / 256, 256, 0, stream>>>(out, ovf,
                                                             (const float*)partials, G);
    } else {
        hipMemsetAsync(d_out, 0, outBytes, stream);
        dim3 ggrid(OS / TZ, OS / TY);
        warp_gather<<<ggrid, 512, 0, stream>>>(x, flow, mask, out, out, 1);
        dim3 pgrid(SRC_W / TW, SRC_H / TH, (SRC_D - ZSPLIT) / ZC);
        warp_push_plane<<<pgrid, 256, 0, stream>>>(x, flow, mask, out);
    }
}

// Round 6
// 483.972 us; speedup vs baseline: 1.1338x; 1.0268x over previous
//
#include <hip/hip_runtime.h>

// WarpingLayer_3stacks: trilinear scatter-splat (grid_push) of
// intensities = [x*mask, mask] into 128^3, coords = flow + meshgrid.
// Input 384x128x128 f32. Output [1,2,128,128,128] f32.
//
// R1: global f32 atomicAdd ~22G/s is the wall -> privatize in LDS.
// R3/R4: gather stuck ~190us latency-bound: 30 serial iters, guarded loads.
// R5: 7 fat iters of unconditional float4 loads; gather plain-stores the
//     whole volume (no memset / no full-volume combine); far corners ->
//     record lists applied by a tail kernel; XOR bank swizzle for the
//     stride-4 LDS atomics; plane = float4 + 2-stage partial reduction.

#define OS    128
#define OS3   (OS * OS * OS)
#define SRC_D 384
#define SRC_H 128
#define SRC_W 128
#define NSRC  (SRC_D * SRC_H * SRC_W)
#define ZSPLIT 128
#define PLANE_CELLS (OS * OS)

// gather tiling: block owns out[z0:z0+4][y0:y0+4][0:128]
#define TZ 4
#define TY 4
#define HALO 3
#define NJOBS 100          // 10 z-rows x 10 y-rows scan window
#define GITER 7            // ceil(100/16) row-jobs per 512-thr block

#define REG_CAP 512        // per-gather-block record region
#define LCAP    65536      // shared overflow list
#define GPLANE  256        // plane slab groups (1 z-slab each)
#define SLICES  16         // plane reduction fan-in stage 1

// ws layout (bytes)
#define OFF_CNT    0
#define OFF_COUNTS 1024
#define OFF_REGS   8192
#define OFF_LIST   (OFF_REGS + 1024 * REG_CAP * 16)          //  8,396,800
#define OFF_TMP    (OFF_LIST + LCAP * 16)                    //  9,445,376
#define OFF_PART   (16 * 1024 * 1024)
#define WS_NEED    (OFF_PART + GPLANE * 2 * PLANE_CELLS * 4) // 50,331,648

// x-dim LDS bank swizzle: float4 lanes stride 4 words -> 8-way conflict.
// XOR bits [1:0] with bits [6:5]: involution, spreads to all 32 banks.
__device__ __forceinline__ int swz(int c) { return c ^ ((c >> 5) & 3); }

// un-permute a float4 loaded from swizzled layout (k = (phys>>5)&3)
__device__ __forceinline__ float4 swz4(float4 v, int k) {
    switch (k & 3) {
        case 1:  return make_float4(v.y, v.x, v.w, v.z);
        case 2:  return make_float4(v.z, v.w, v.x, v.y);
        case 3:  return make_float4(v.w, v.z, v.y, v.x);
        default: return v;
    }
}

// ---------------- gather: source z<128, owns & plain-stores out ------------
__global__ __launch_bounds__(512) void warp_gather(
    const float* __restrict__ x, const float* __restrict__ flow,
    const float* __restrict__ mask, float* __restrict__ out,
    unsigned* __restrict__ gcnt, int* __restrict__ counts,
    int4* __restrict__ regs, int4* __restrict__ list)
{
    __shared__ float acc[2 * TZ * TY * OS];   // 16 KB, x swizzled
    __shared__ int scnt;

    const int tid = threadIdx.x;
    if (tid == 0) scnt = 0;
    {
        float4* a4 = (float4*)acc;
        a4[tid]       = make_float4(0, 0, 0, 0);
        a4[tid + 512] = make_float4(0, 0, 0, 0);
    }
    __syncthreads();

    const int z0 = blockIdx.x * TZ;
    const int y0 = blockIdx.y * TY;
    const int bl = blockIdx.y * gridDim.x + blockIdx.x;
    const int wq = tid & 31;          // w quad: handles w = 4*wq .. +3
    const int slot = tid >> 5;        // 0..15 row-job slot

    const float4* __restrict__ fz4 = (const float4*)flow;
    const float4* __restrict__ fy4 = (const float4*)(flow + NSRC);
    const float4* __restrict__ fx4 = (const float4*)(flow + 2 * NSRC);
    const float4* __restrict__ m4p = (const float4*)mask;
    const float4* __restrict__ x4p = (const float4*)x;

    for (int it = 0; it < GITER; ++it) {
        int j = it * 16 + slot;
        int dz = j / 10, dyy = j - dz * 10;
        int zzr = z0 - HALO + dz;
        int hhr = y0 - HALO + dyy;
        int zz = min(max(zzr, 0), ZSPLIT - 1);
        int hh = min(max(hhr, 0), OS - 1);
        bool vrow = (j < NJOBS) && (zzr >= 0) && (zzr < ZSPLIT) &&
                    (hhr >= 0) && (hhr < OS);
        bool home = vrow && (zzr >= z0) && (zzr < z0 + TZ) &&
                    (hhr >= y0) && (hhr < y0 + TY);

        int idx4 = (((zz << 14) + (hh << 7)) >> 2) + wq;
        float4 vfz = fz4[idx4];       // unconditional clamped-address loads
        float4 vfy = fy4[idx4];
        float4 vfx = fx4[idx4];
        float4 vm  = m4p[idx4];
        float4 vx  = x4p[idx4];

        if (!vrow) continue;

        #pragma unroll
        for (int p = 0; p < 4; ++p) {
            float fzl = ((float*)&vfz)[p];
            float fyl = ((float*)&vfy)[p];
            float gz = fzl + (float)zz;
            float gy = fyl + (float)hh;
            float fzf = floorf(gz), fyf = floorf(gy);
            float ffz = gz - fzf, ffy = gy - fyf;
            int iz0 = (int)fzf, iy0 = (int)fyf;

            int cz0 = min(max(iz0,     0), OS - 1);
            int cz1 = min(max(iz0 + 1, 0), OS - 1);
            int cy0 = min(max(iy0,     0), OS - 1);
            int cy1 = min(max(iy0 + 1, 0), OS - 1);

            bool zin = (cz1 >= z0) && (cz0 < z0 + TZ);
            bool yin = (cy1 >= y0) && (cy0 < y0 + TY);
            if (!home && !(zin && yin)) continue;

            int w = wq * 4 + p;
            float gx = ((float*)&vfx)[p] + (float)w;
            float fxf = floorf(gx);
            float ffx = gx - fxf;
            int ix0 = (int)fxf;
            int cx0 = min(max(ix0,     0), OS - 1);
            int cx1 = min(max(ix0 + 1, 0), OS - 1);

            float m = ((float*)&vm)[p];
            float v = ((float*)&vx)[p] * m;

            #pragma unroll
            for (int d2 = 0; d2 < 2; ++d2) {
                int cz = d2 ? cz1 : cz0;
                float wz = d2 ? ffz : 1.0f - ffz;
                bool nz = (cz - zz <= HALO) && (zz - cz <= HALO);
                int uz = cz - z0;
                #pragma unroll
                for (int e2 = 0; e2 < 2; ++e2) {
                    int cy = e2 ? cy1 : cy0;
                    float wzy = wz * (e2 ? ffy : 1.0f - ffy);
                    bool ny = (cy - hh <= HALO) && (hh - cy <= HALO);
                    int uy = cy - y0;
                    bool nearc = nz && ny;
                    #pragma unroll
                    for (int f2 = 0; f2 < 2; ++f2) {
                        int cx = f2 ? cx1 : cx0;
                        float wgt = wzy * (f2 ? ffx : 1.0f - ffx);
                        if (nearc) {
                            if ((unsigned)uz < TZ && (unsigned)uy < TY) {
                                int off = ((uz * TY + uy) << 7) + swz(cx);
                                atomicAdd(&acc[off],                     v * wgt);
                                atomicAdd(&acc[(TZ * TY << 7) + off],    m * wgt);
                            }
                        } else if (home) {
                            int4 r;
                            r.x = (cz << 14) + (cy << 7) + cx;
                            r.y = __float_as_int(v * wgt);
                            r.z = __float_as_int(m * wgt);
                            r.w = 0;
                            int s = atomicAdd(&scnt, 1);
                            if (s < REG_CAP) regs[bl * REG_CAP + s] = r;
                            else {
                                unsigned g = atomicAdd(gcnt, 1u);
                                if (g < LCAP) list[g] = r;
                            }
                        }
                    }
                }
            }
        }
    }

    __syncthreads();
    if (tid == 0) counts[bl] = min(scnt, REG_CAP);

    // plain-store owned tile (entire volume covered by the tile grid)
    float4* a4 = (float4*)acc;
    #pragma unroll
    for (int s = 0; s < 2; ++s) {
        int jf = tid + s * 512;            // f4 idx 0..1023
        int row = jf >> 5;                 // 0..31
        int ch = row >> 4, uz = (row >> 2) & 3, uy = row & 3;
        int colq = jf & 31;
        int k = (colq >> 3) & 3;
        float4 vv = swz4(a4[jf], k);
        int o4 = (ch * OS3 + ((z0 + uz) << 14) + ((y0 + uy) << 7) + colq * 4) >> 2;
        ((float4*)out)[o4] = vv;
    }
}

// ------- plane: source z>=128, gz>=127 -> z=127 plane partials in LDS -------
__global__ __launch_bounds__(1024) void warp_plane(
    const float* __restrict__ x, const float* __restrict__ flow,
    const float* __restrict__ mask, float* __restrict__ partials,
    unsigned* __restrict__ gcnt, int4* __restrict__ list)
{
    __shared__ float pl[PLANE_CELLS];     // 64 KB, x swizzled

    const int tid = threadIdx.x;
    const int ch = blockIdx.y;
    float4* p4 = (float4*)pl;
    #pragma unroll
    for (int s = 0; s < 4; ++s) p4[tid + s * 1024] = make_float4(0, 0, 0, 0);
    __syncthreads();

    const int z  = ZSPLIT + blockIdx.x;
    const int wq = tid & 31;
    const int r0 = tid >> 5;              // 0..31
    const int lane = tid & 63;

    const float4* __restrict__ fz4 = (const float4*)flow;
    const float4* __restrict__ fy4 = (const float4*)(flow + NSRC);
    const float4* __restrict__ fx4 = (const float4*)(flow + 2 * NSRC);
    const float4* __restrict__ m4p = (const float4*)mask;
    const float4* __restrict__ v4p = (const float4*)(ch ? mask : x);

    for (int s = 0; s < 4; ++s) {
        int row = r0 + s * 32;
        int idx4 = (((z << 14) + (row << 7)) >> 2) + wq;
        float4 vfz = fz4[idx4];
        float4 vfy = fy4[idx4];
        float4 vfx = fx4[idx4];
        float4 vm  = m4p[idx4];
        float4 vv  = v4p[idx4];

        #pragma unroll
        for (int p = 0; p < 4; ++p) {
            float gz = ((float*)&vfz)[p] + (float)z;
            float gy = ((float*)&vfy)[p] + (float)row;
            float gx = ((float*)&vfx)[p] + (float)(wq * 4 + p);
            float m  = ((float*)&vm)[p];
            float vl = ((float*)&vv)[p];

            float fyf = floorf(gy), fxf = floorf(gx);
            float ffy = gy - fyf, ffx = gx - fxf;
            int iy0 = (int)fyf, ix0 = (int)fxf;
            int cy0 = min(max(iy0,     0), OS - 1);
            int cy1 = min(max(iy0 + 1, 0), OS - 1);
            int cx0 = min(max(ix0,     0), OS - 1);
            int cx1 = min(max(ix0 + 1, 0), OS - 1);

            if (gz >= (float)(OS - 1)) {   // both z-corners clamp -> wz sums to 1
                float v = ch ? m : vl * m;
                int sx0 = swz(cx0), sx1 = swz(cx1);
                atomicAdd(&pl[(cy0 << 7) + sx0], v * (1.0f - ffy) * (1.0f - ffx));
                atomicAdd(&pl[(cy0 << 7) + sx1], v * (1.0f - ffy) * ffx);
                atomicAdd(&pl[(cy1 << 7) + sx0], v * ffy * (1.0f - ffx));
                atomicAdd(&pl[(cy1 << 7) + sx1], v * ffy * ffx);
            } else if (ch == 0) {
                // rare boundary points (gz<127): append 8 trilinear records,
                // ballot-aggregated counter bump
                float v0 = vl * m;
                float fzf = floorf(gz);
                float ffz = gz - fzf;
                int iz0 = (int)fzf;

                unsigned long long b = __ballot(1);
                int leader = __ffsll((unsigned long long)b) - 1;
                int pre = __popcll(b & ((1ULL << lane) - 1));
                unsigned base = 0;
                if (lane == leader) base = atomicAdd(gcnt, (unsigned)__popcll(b) * 8u);
                base = (unsigned)__shfl((int)base, leader);
                unsigned my = base + (unsigned)pre * 8u;

                int t = 0;
                #pragma unroll
                for (int d2 = 0; d2 < 2; ++d2) {
                    int cz = min(max(iz0 + d2, 0), OS - 1);
                    float wz = d2 ? ffz : 1.0f - ffz;
                    #pragma unroll
                    for (int e2 = 0; e2 < 2; ++e2) {
                        int cy = e2 ? cy1 : cy0;
                        float wzy = wz * (e2 ? ffy : 1.0f - ffy);
                        #pragma unroll
                        for (int f2 = 0; f2 < 2; ++f2) {
                            int cx = f2 ? cx1 : cx0;
                            float wgt = wzy * (f2 ? ffx : 1.0f - ffx);
                            unsigned slot = my + t;
                            if (slot < LCAP) {
                                int4 r;
                                r.x = (cz << 14) + (cy << 7) + cx;
                                r.y = __float_as_int(v0 * wgt);
                                r.z = __float_as_int(m * wgt);
                                r.w = 0;
                                list[slot] = r;
                            }
                            ++t;
                        }
                    }
                }
            }
        }
    }

    __syncthreads();
    float4* dst = (float4*)(partials + (size_t)(blockIdx.x * 2 + ch) * PLANE_CELLS);
    #pragma unroll
    for (int s = 0; s < 4; ++s) dst[tid + s * 1024] = p4[tid + s * 1024];
}

// ---- plane partial reduction, stage 1: 256 -> 16 slices ----
__global__ __launch_bounds__(256) void plane_reduce1(
    const float4* __restrict__ partials, float4* __restrict__ tmp)
{
    int t = blockIdx.x * 256 + threadIdx.x;        // 0..131071
    int slice = t >> 13;
    int rem = t & 8191;
    int ch = rem >> 12;
    int c4 = rem & 4095;
    float4 s = make_float4(0, 0, 0, 0);
    #pragma unroll
    for (int g = 0; g < GPLANE / SLICES; ++g) {
        float4 v = partials[((size_t)((slice * (GPLANE / SLICES) + g) * 2 + ch)) * 4096 + c4];
        s.x += v.x; s.y += v.y; s.z += v.z; s.w += v.w;
    }
    tmp[(size_t)(slice * 2 + ch) * 4096 + c4] = s;
}

// ---- stage 2: 16 -> out (z=127 plane), with swizzle un-permute ----
__global__ __launch_bounds__(256) void plane_reduce2(
    float* __restrict__ out, const float4* __restrict__ tmp)
{
    int t = blockIdx.x * 256 + threadIdx.x;        // 0..8191
    int ch = t >> 12;
    int c4 = t & 4095;
    float4 s = make_float4(0, 0, 0, 0);
    #pragma unroll
    for (int sl = 0; sl < SLICES; ++sl) {
        float4 v = tmp[(size_t)(sl * 2 + ch) * 4096 + c4];
        s.x += v.x; s.y += v.y; s.z += v.z; s.w += v.w;
    }
    int k = (c4 >> 3) & 3;
    float4 w = swz4(s, k);
    int o4 = (ch * OS3 + ((OS - 1) << 14)) / 4 + c4;
    float4 a = ((float4*)out)[o4];
    a.x += w.x; a.y += w.y; a.z += w.z; a.w += w.w;
    ((float4*)out)[o4] = a;
}

// ---- apply overflow records (per-block regions + shared list) ----
__global__ __launch_bounds__(256) void apply_records(
    float* __restrict__ out, const unsigned* __restrict__ gcnt,
    const int* __restrict__ counts, const int4* __restrict__ regs,
    const int4* __restrict__ list)
{
    int b = blockIdx.x;
    if (b < 1024) {
        int n = counts[b];
        const int4* r = regs + (size_t)b * REG_CAP;
        for (int i = threadIdx.x; i < n; i += 256) {
            int4 q = r[i];
            atomicAdd(out + q.x,       __int_as_float(q.y));
            atomicAdd(out + OS3 + q.x, __int_as_float(q.z));
        }
    } else {
        unsigned n = *gcnt;
        if (n > LCAP) n = LCAP;
        for (unsigned i = (unsigned)(b - 1024) * 256 + threadIdx.x; i < n; i += 8 * 256) {
            int4 q = list[i];
            atomicAdd(out + q.x,       __int_as_float(q.y));
            atomicAdd(out + OS3 + q.x, __int_as_float(q.z));
        }
    }
}

// ---------------- fallback (ws too small): naive merged scatter ------------
__global__ __launch_bounds__(256) void warp_push_naive(
    const float* __restrict__ x, const float* __restrict__ flow,
    const float* __restrict__ mask, float* __restrict__ out, int N)
{
    int idx = blockIdx.x * blockDim.x + threadIdx.x;
    if (idx >= N) return;
    int w = idx & 127, h = (idx >> 7) & 127, z = idx >> 14;
    float gz = flow[idx] + (float)z;
    float gy = flow[N + idx] + (float)h;
    float gx = flow[2 * N + idx] + (float)w;
    float m = mask[idx];
    float v0 = x[idx] * m;
    float fz0 = floorf(gz), fy0 = floorf(gy), fx0 = floorf(gx);
    float fz = gz - fz0, fy = gy - fy0, fx = gx - fx0;
    int iz0 = (int)fz0, iy0 = (int)fy0, ix0 = (int)fx0;
    #pragma unroll
    for (int dz = 0; dz < 2; ++dz) {
        int cz = min(max(iz0 + dz, 0), OS - 1);
        float wz = dz ? fz : 1.0f - fz;
        #pragma unroll
        for (int dy = 0; dy < 2; ++dy) {
            int cy = min(max(iy0 + dy, 0), OS - 1);
            float wzy = wz * (dy ? fy : 1.0f - fy);
            #pragma unroll
            for (int dx = 0; dx < 2; ++dx) {
                int cx = min(max(ix0 + dx, 0), OS - 1);
                float wgt = wzy * (dx ? fx : 1.0f - fx);
                int o = (cz << 14) + (cy << 7) + cx;
                atomicAdd(out + o,       v0 * wgt);
                atomicAdd(out + OS3 + o, m * wgt);
            }
        }
    }
}

extern "C" void kernel_launch(void* const* d_in, const int* in_sizes, int n_in,
                              void* d_out, int out_size, void* d_ws, size_t ws_size,
                              hipStream_t stream) {
    (void)in_sizes; (void)n_in; (void)out_size;
    const float* x    = (const float*)d_in[0];
    const float* flow = (const float*)d_in[1];
    const float* mask = (const float*)d_in[2];
    float* out = (float*)d_out;

    if (ws_size >= (size_t)WS_NEED) {
        char* wsb = (char*)d_ws;
        unsigned* gcnt = (unsigned*)(wsb + OFF_CNT);
        int* counts    = (int*)(wsb + OFF_COUNTS);
        int4* regs     = (int4*)(wsb + OFF_REGS);
        int4* list     = (int4*)(wsb + OFF_LIST);
        float4* tmp    = (float4*)(wsb + OFF_TMP);
        float* parts   = (float*)(wsb + OFF_PART);

        hipMemsetAsync(d_ws, 0, 64, stream);   // zero list counter

        warp_gather<<<dim3(OS / TZ, OS / TY), 512, 0, stream>>>(
            x, flow, mask, out, gcnt, counts, regs, list);
        warp_plane<<<dim3(GPLANE, 2), 1024, 0, stream>>>(
            x, flow, mask, parts, gcnt, list);
        plane_reduce1<<<512, 256, 0, stream>>>((const float4*)parts, tmp);
        plane_reduce2<<<32, 256, 0, stream>>>(out, (const float4*)tmp);
        apply_records<<<1024 + 8, 256, 0, stream>>>(out, gcnt, counts, regs, list);
    } else {
        hipMemsetAsync(d_out, 0, (size_t)2 * OS3 * sizeof(float), stream);
        warp_push_naive<<<NSRC / 256, 256, 0, stream>>>(x, flow, mask, out, NSRC);
    }
}